// Round 3
// baseline (55.342 us; speedup 1.0000x reference)
//
#include <hip/hip_runtime.h>

// Problem shape (fixed by setup_inputs): U[8,64,256,256] f32, theta[8,2,65536] f32,
// out_h = out_w = 256. Output [N,C,256,256] f32 == flat [N*HWo, C] buffer.
constexpr int N   = 8;
constexpr int C   = 64;
constexpr int H   = 256;
constexpr int W   = 256;
constexpr int OH  = 256;
constexpr int OW  = 256;
constexpr int HWo = OH * OW;

// One sample is handled by 16 consecutive lanes; each lane owns 4 channels
// (float4, 16 B). A 16-lane group therefore reads each gathered row as one
// contiguous 256 B chunk, and a full wave (4 samples) writes 1 KB contiguous.
__global__ __launch_bounds__(256) void stn_kernel(
    const float* __restrict__ U,
    const float* __restrict__ theta,
    float* __restrict__ out)
{
    const int t  = blockIdx.x * blockDim.x + threadIdx.x;
    const int s  = t >> 4;              // sample index in [0, N*HWo)
    const int cg = (t & 15) << 2;       // channel base: 0,4,...,60

    const int n  = s >> 16;             // s / HWo  (HWo = 65536)
    const int p  = s & (HWo - 1);       // position within image
    const int ow = p & (OW - 1);
    const int oh = p >> 8;

    // identity grid: linspace(-1,1,256)[i] = i*(2/255) - 1
    const float gx = (float)ow * (2.0f / 255.0f) - 1.0f;
    const float gy = (float)oh * (2.0f / 255.0f) - 1.0f;

    float x = theta[(n * 2 + 0) * HWo + p] + gx;
    float y = theta[(n * 2 + 1) * HWo + p] + gy;

    // map to pixel coords: (v + 1) * (dim-1) / 2   (*0.5f is exact /2)
    x = (x + 1.0f) * (float)(W - 1) * 0.5f;
    y = (y + 1.0f) * (float)(H - 1) * 0.5f;

    // faithful to reference: cast-to-int THEN clip; extrapolation weights
    // (possibly <0 or >1) are kept as-is.
    const int x0 = min(max((int)floorf(x), 0), W - 2);
    const int x1 = min(max((int)ceilf(x),  0), W - 1);
    const int y0 = min(max((int)floorf(y), 0), H - 2);
    const int y1 = min(max((int)ceilf(y),  0), H - 1);

    const float x0f = (float)x0, x1f = (float)x1;
    const float y0f = (float)y0, y1f = (float)y1;

    const float wa = (x1f - x) * (y1f - y);
    const float wb = (x1f - x) * (y - y0f);
    const float wc = (x - x0f) * (y1f - y);
    const float wd = (x - x0f) * (y - y0f);

    // flat NHWC-style gather: im_flat = U.reshape(-1, C); element = U[idx*C + c]
    const int base = n * (H * W);
    const int ia = (base + y0 * W + x0) * C + cg;
    const int ib = (base + y1 * W + x0) * C + cg;
    const int ic = (base + y0 * W + x1) * C + cg;
    const int id = (base + y1 * W + x1) * C + cg;

    const float4 A = *(const float4*)(U + ia);
    const float4 B = *(const float4*)(U + ib);
    const float4 Cv = *(const float4*)(U + ic);
    const float4 D = *(const float4*)(U + id);

    float4 o;
    o.x = wa * A.x + wb * B.x + wc * Cv.x + wd * D.x;
    o.y = wa * A.y + wb * B.y + wc * Cv.y + wd * D.y;
    o.z = wa * A.z + wb * B.z + wc * Cv.z + wd * D.z;
    o.w = wa * A.w + wb * B.w + wc * Cv.w + wd * D.w;

    *(float4*)(out + (size_t)s * C + cg) = o;
}

extern "C" void kernel_launch(void* const* d_in, const int* in_sizes, int n_in,
                              void* d_out, int out_size, void* d_ws, size_t ws_size,
                              hipStream_t stream)
{
    const float* U     = (const float*)d_in[0];
    const float* theta = (const float*)d_in[1];
    float* out         = (float*)d_out;

    // total threads = N*HWo samples * 16 lanes/sample = 8,388,608
    const int total   = N * HWo * 16;
    const int block   = 256;
    const int grid    = total / block;   // 32768

    stn_kernel<<<grid, block, 0, stream>>>(U, theta, out);
}

// Round 4
// 54.420 us; speedup vs baseline: 1.0169x; 1.0169x over previous
//
#include <hip/hip_runtime.h>

// Problem shape (fixed by setup_inputs): U[8,64,256,256] f32, theta[8,2,65536] f32,
// out_h = out_w = 256. Output [N,C,256,256] f32 == flat [N*HWo, C] buffer.
constexpr int N   = 8;
constexpr int C   = 64;
constexpr int H   = 256;
constexpr int W   = 256;
constexpr int OH  = 256;
constexpr int OW  = 256;
constexpr int HWo = OH * OW;

// Native vector type so __builtin_nontemporal_store emits one global_store_dwordx4 nt.
typedef float f32x4 __attribute__((ext_vector_type(4)));

// One sample is handled by 16 consecutive lanes; each lane owns 4 channels
// (float4, 16 B). A 16-lane group therefore reads each gathered row as one
// contiguous 256 B chunk, and a full wave (4 samples) writes 1 KB contiguous.
// Output is write-once never-read: stored non-temporally so the 131 MB write
// stream doesn't evict U (134 MB, L3-resident) from L2/L3.
__global__ __launch_bounds__(256) void stn_kernel(
    const float* __restrict__ U,
    const float* __restrict__ theta,
    float* __restrict__ out)
{
    const int t  = blockIdx.x * blockDim.x + threadIdx.x;
    const int s  = t >> 4;              // sample index in [0, N*HWo)
    const int cg = (t & 15) << 2;       // channel base: 0,4,...,60

    const int n  = s >> 16;             // s / HWo  (HWo = 65536)
    const int p  = s & (HWo - 1);       // position within image
    const int ow = p & (OW - 1);
    const int oh = p >> 8;

    // identity grid: linspace(-1,1,256)[i] = i*(2/255) - 1
    const float gx = (float)ow * (2.0f / 255.0f) - 1.0f;
    const float gy = (float)oh * (2.0f / 255.0f) - 1.0f;

    float x = theta[(n * 2 + 0) * HWo + p] + gx;
    float y = theta[(n * 2 + 1) * HWo + p] + gy;

    // map to pixel coords: (v + 1) * (dim-1) / 2   (*0.5f is exact /2)
    x = (x + 1.0f) * (float)(W - 1) * 0.5f;
    y = (y + 1.0f) * (float)(H - 1) * 0.5f;

    // faithful to reference: cast-to-int THEN clip; extrapolation weights
    // (possibly <0 or >1) are kept as-is.
    const int x0 = min(max((int)floorf(x), 0), W - 2);
    const int x1 = min(max((int)ceilf(x),  0), W - 1);
    const int y0 = min(max((int)floorf(y), 0), H - 2);
    const int y1 = min(max((int)ceilf(y),  0), H - 1);

    const float x0f = (float)x0, x1f = (float)x1;
    const float y0f = (float)y0, y1f = (float)y1;

    const float wa = (x1f - x) * (y1f - y);
    const float wb = (x1f - x) * (y - y0f);
    const float wc = (x - x0f) * (y1f - y);
    const float wd = (x - x0f) * (y - y0f);

    // flat NHWC-style gather: im_flat = U.reshape(-1, C); element = U[idx*C + c]
    const int base = n * (H * W);
    const int ia = (base + y0 * W + x0) * C + cg;
    const int ib = (base + y1 * W + x0) * C + cg;
    const int ic = (base + y0 * W + x1) * C + cg;
    const int id = (base + y1 * W + x1) * C + cg;

    const f32x4 A  = *(const f32x4*)(U + ia);
    const f32x4 B  = *(const f32x4*)(U + ib);
    const f32x4 Cv = *(const f32x4*)(U + ic);
    const f32x4 D  = *(const f32x4*)(U + id);

    f32x4 o = wa * A + wb * B + wc * Cv + wd * D;

    __builtin_nontemporal_store(o, (f32x4*)(out + (size_t)s * C + cg));
}

extern "C" void kernel_launch(void* const* d_in, const int* in_sizes, int n_in,
                              void* d_out, int out_size, void* d_ws, size_t ws_size,
                              hipStream_t stream)
{
    const float* U     = (const float*)d_in[0];
    const float* theta = (const float*)d_in[1];
    float* out         = (float*)d_out;

    // total threads = N*HWo samples * 16 lanes/sample = 8,388,608
    const int total   = N * HWo * 16;
    const int block   = 256;
    const int grid    = total / block;   // 32768

    stn_kernel<<<grid, block, 0, stream>>>(U, theta, out);
}

// Round 5
// 46.900 us; speedup vs baseline: 1.1800x; 1.1603x over previous
//
#include <hip/hip_runtime.h>

// Problem shape (fixed): U[8,64,256,256] f32, theta[8,2,65536] f32, out 256x256.
// Output [N,C,256,256] f32 == flat [N*HWo, C] buffer (reference's im_flat view).
constexpr int N   = 8;
constexpr int C   = 64;
constexpr int H   = 256;
constexpr int W   = 256;
constexpr int OH  = 256;
constexpr int OW  = 256;
constexpr int HWo = OH * OW;
constexpr int SAMPLES = N * HWo;              // 524288
constexpr int BLOCK   = 256;
constexpr int GRID    = SAMPLES / 2 * 16 / BLOCK;  // 16384 (2 samples/thread)
constexpr int GRID_PER_XCD = GRID / 8;        // 2048 = exactly one image per XCD

typedef float f32x4 __attribute__((ext_vector_type(4)));

// 16 lanes per sample-pair; each lane owns 4 channels (float4) of BOTH samples.
// 2 samples/thread -> 8 independent 16B gathers in flight (2x MLP vs R3).
// XCD swizzle: blockIdx round-robins over 8 XCDs; remap so XCD k gets the
// contiguous chunk k == image k -> per-L2 working set 16.7 MB instead of 134 MB.
__global__ __launch_bounds__(256) void stn_kernel(
    const float* __restrict__ U,
    const float* __restrict__ theta,
    float* __restrict__ out)
{
    const int b  = blockIdx.x;
    const int bs = (b & 7) * GRID_PER_XCD + (b >> 3);   // bijective (GRID % 8 == 0)

    const int t  = bs * BLOCK + threadIdx.x;
    const int q  = t >> 4;              // sample-pair index
    const int cg = (t & 15) << 2;       // channel base: 0,4,...,60

    const int s0 = q << 1;              // even sample
    const int n  = s0 >> 16;            // image index (HWo = 65536)
    const int p0 = s0 & (HWo - 1);      // even -> ow0 even, pair shares row
    const int ow0 = p0 & (OW - 1);
    const int oh0 = p0 >> 8;

    // theta for both samples: adjacent -> one float2 each for x and y
    const float2 tx = *(const float2*)(theta + (size_t)(n * 2 + 0) * HWo + p0);
    const float2 ty = *(const float2*)(theta + (size_t)(n * 2 + 1) * HWo + p0);

    // identity grid: linspace(-1,1,256)[i] = i*(2/255) - 1
    const float gx0 = (float)ow0 * (2.0f / 255.0f) - 1.0f;
    const float gx1 = (float)(ow0 + 1) * (2.0f / 255.0f) - 1.0f;
    const float gy  = (float)oh0 * (2.0f / 255.0f) - 1.0f;

    // pixel coords
    float xA = (tx.x + gx0 + 1.0f) * (float)(W - 1) * 0.5f;
    float xB = (tx.y + gx1 + 1.0f) * (float)(W - 1) * 0.5f;
    float yA = (ty.x + gy  + 1.0f) * (float)(H - 1) * 0.5f;
    float yB = (ty.y + gy  + 1.0f) * (float)(H - 1) * 0.5f;

    // faithful: int-cast then clip; extrapolation weights kept as-is
    const int x0A = min(max((int)floorf(xA), 0), W - 2);
    const int x1A = min(max((int)ceilf(xA),  0), W - 1);
    const int y0A = min(max((int)floorf(yA), 0), H - 2);
    const int y1A = min(max((int)ceilf(yA),  0), H - 1);
    const int x0B = min(max((int)floorf(xB), 0), W - 2);
    const int x1B = min(max((int)ceilf(xB),  0), W - 1);
    const int y0B = min(max((int)floorf(yB), 0), H - 2);
    const int y1B = min(max((int)ceilf(yB),  0), H - 1);

    // flat gather: element = U[(n*H*W + y*W + x)*C + c]
    const int base = n * (H * W);
    const int iaA = (base + y0A * W + x0A) * C + cg;
    const int ibA = (base + y1A * W + x0A) * C + cg;
    const int icA = (base + y0A * W + x1A) * C + cg;
    const int idA = (base + y1A * W + x1A) * C + cg;
    const int iaB = (base + y0B * W + x0B) * C + cg;
    const int ibB = (base + y1B * W + x0B) * C + cg;
    const int icB = (base + y0B * W + x1B) * C + cg;
    const int idB = (base + y1B * W + x1B) * C + cg;

    // issue all 8 gathers back-to-back (independent -> 8 outstanding misses)
    const f32x4 Aa = *(const f32x4*)(U + iaA);
    const f32x4 Ba = *(const f32x4*)(U + ibA);
    const f32x4 Ca = *(const f32x4*)(U + icA);
    const f32x4 Da = *(const f32x4*)(U + idA);
    const f32x4 Ab = *(const f32x4*)(U + iaB);
    const f32x4 Bb = *(const f32x4*)(U + ibB);
    const f32x4 Cb = *(const f32x4*)(U + icB);
    const f32x4 Db = *(const f32x4*)(U + idB);

    // weights
    const float waA = ((float)x1A - xA) * ((float)y1A - yA);
    const float wbA = ((float)x1A - xA) * (yA - (float)y0A);
    const float wcA = (xA - (float)x0A) * ((float)y1A - yA);
    const float wdA = (xA - (float)x0A) * (yA - (float)y0A);
    const float waB = ((float)x1B - xB) * ((float)y1B - yB);
    const float wbB = ((float)x1B - xB) * (yB - (float)y0B);
    const float wcB = (xB - (float)x0B) * ((float)y1B - yB);
    const float wdB = (xB - (float)x0B) * (yB - (float)y0B);

    const f32x4 oA = waA * Aa + wbA * Ba + wcA * Ca + wdA * Da;
    const f32x4 oB = waB * Ab + wbB * Bb + wcB * Cb + wdB * Db;

    float* outp = out + (size_t)s0 * C + cg;
    __builtin_nontemporal_store(oA, (f32x4*)outp);
    __builtin_nontemporal_store(oB, (f32x4*)(outp + C));
}

extern "C" void kernel_launch(void* const* d_in, const int* in_sizes, int n_in,
                              void* d_out, int out_size, void* d_ws, size_t ws_size,
                              hipStream_t stream)
{
    const float* U     = (const float*)d_in[0];
    const float* theta = (const float*)d_in[1];
    float* out         = (float*)d_out;

    stn_kernel<<<GRID, BLOCK, 0, stream>>>(U, theta, out);
}